// Round 1
// baseline (611.836 us; speedup 1.0000x reference)
//
#include <hip/hip_runtime.h>
#include <hip/hip_bf16.h>
#include <math.h>

// MoE top-2 of 8 experts, D=1024, FF=2048 (SwiGLU), T=4096 tokens.
// Pipeline: router(+x cast,+b2 init) -> prefix -> transpose-cast weights ->
// GEMM1 (gather A, fused SwiGLU*w -> U bf16) -> GEMM2 (atomicAdd scatter).

#define T_TOK  4096
#define DMODEL 1024
#define NEXP   8
#define FF     2048
#define FF2    4096

typedef __bf16 bf16_t;
typedef bf16_t bf16x8 __attribute__((ext_vector_type(8)));
typedef float  f32x4  __attribute__((ext_vector_type(4)));

__device__ __forceinline__ void gload_lds16(const void* g, void* l) {
  __builtin_amdgcn_global_load_lds((const __attribute__((address_space(1))) void*)g,
                                   (__attribute__((address_space(3))) void*)l, 16, 0, 0);
}

// ---------------- router: logits, top-2 softmax, bucket-append, x->bf16, out=sum w*b2
__global__ __launch_bounds__(256) void moe_router(
    const float* __restrict__ x, const float* __restrict__ Wr,
    const float* __restrict__ temp, const float* __restrict__ b2,
    bf16_t* __restrict__ xb, float* __restrict__ out,
    int* __restrict__ cnt, int* __restrict__ tok_list, float* __restrict__ w_list)
{
  __shared__ float sWr[DMODEL * NEXP];   // 32 KB, whole router weight
  for (int i = threadIdx.x; i < DMODEL * NEXP; i += 256) sWr[i] = Wr[i];
  __syncthreads();

  int wave = threadIdx.x >> 6, lane = threadIdx.x & 63;
  int t = blockIdx.x * 4 + wave;
  const float* xr = x + (size_t)t * DMODEL;

  f32x4 acc0 = {0.f, 0.f, 0.f, 0.f}, acc1 = {0.f, 0.f, 0.f, 0.f};
  #pragma unroll
  for (int i = 0; i < 16; ++i) {
    int d = lane + 64 * i;                    // coalesced
    float v = xr[d];
    xb[(size_t)t * DMODEL + d] = (bf16_t)v;   // fused cast
    const f32x4* wr = (const f32x4*)&sWr[d * NEXP];
    acc0 += v * wr[0];
    acc1 += v * wr[1];
  }
  #pragma unroll
  for (int off = 32; off; off >>= 1) {
    #pragma unroll
    for (int q = 0; q < 4; ++q) {
      acc0[q] += __shfl_down(acc0[q], off, 64);
      acc1[q] += __shfl_down(acc1[q], off, 64);
    }
  }
  int bi = 0, si = 0; float wb = 0.f, wsc = 0.f;
  if (lane == 0) {
    float invt = 1.f / temp[0];
    float lg[NEXP] = {acc0[0], acc0[1], acc0[2], acc0[3],
                      acc1[0], acc1[1], acc1[2], acc1[3]};
    float best = -3.4e38f, sec = -3.4e38f;
    #pragma unroll
    for (int e = 0; e < NEXP; ++e) {
      float l = lg[e] * invt;
      if (l > best)     { sec = best; si = bi; best = l; bi = e; }
      else if (l > sec) { sec = l; si = e; }
    }
    float ex = expf(sec - best);          // top-2 softmax
    wb  = 1.f / (1.f + ex);
    wsc = ex  / (1.f + ex);
    int p0 = atomicAdd(&cnt[bi], 1);
    tok_list[bi * T_TOK + p0] = t; w_list[bi * T_TOK + p0] = wb;
    int p1 = atomicAdd(&cnt[si], 1);
    tok_list[si * T_TOK + p1] = t; w_list[si * T_TOK + p1] = wsc;
  }
  bi  = __shfl(bi, 0, 64);  si  = __shfl(si, 0, 64);
  wb  = __shfl(wb, 0, 64);  wsc = __shfl(wsc, 0, 64);
  const float* b2a = b2 + (size_t)bi * DMODEL;
  const float* b2b = b2 + (size_t)si * DMODEL;
  float* orow = out + (size_t)t * DMODEL;
  #pragma unroll
  for (int i = 0; i < 16; ++i) {
    int d = lane + 64 * i;
    orow[d] = wb * b2a[d] + wsc * b2b[d];   // init out with weighted b2
  }
}

__global__ void moe_prefix(const int* __restrict__ cnt, int* __restrict__ offs) {
  if (threadIdx.x == 0) {
    int s = 0;
    for (int e = 0; e < NEXP; ++e) { offs[e] = s; s += cnt[e]; }
    offs[NEXP] = s;
  }
}

// ---------------- transpose-cast: fp32 [R][C] -> bf16 [C][R], per blockIdx.z slice
__global__ __launch_bounds__(256) void tcast64(
    const float* __restrict__ in, bf16_t* __restrict__ outp, int R, int C)
{
  __shared__ float tile[64][65];            // +1 pad: conflict-free transpose
  const float* inp = in + (size_t)blockIdx.z * R * C;
  bf16_t* op = outp + (size_t)blockIdx.z * R * C;
  int c0 = blockIdx.x * 64, r0 = blockIdx.y * 64;
  int tx = threadIdx.x & 63, ty = threadIdx.x >> 6;
  #pragma unroll
  for (int j = 0; j < 64; j += 4)
    tile[ty + j][tx] = inp[(size_t)(r0 + ty + j) * C + c0 + tx];
  __syncthreads();
  #pragma unroll
  for (int j = 0; j < 64; j += 4)
    op[(size_t)(c0 + ty + j) * R + r0 + tx] = (bf16_t)tile[tx][ty + j];
}

// ---------------- GEMM1: gathered x rows [cnt x 1024] * W1t[e] -> SwiGLU*w -> U bf16
// Block: 128 rows x (64 a-cols + 64 g-cols). 4 waves of 32 rows x 128 cols.
__global__ __launch_bounds__(256) void moe_gemm1(
    const bf16_t* __restrict__ xb, const bf16_t* __restrict__ W1t,
    const float* __restrict__ b1, const int* __restrict__ cnt,
    const int* __restrict__ offs, const int* __restrict__ tok_list,
    const float* __restrict__ w_list, bf16_t* __restrict__ U,
    int e_base, long estride)
{
  int e = e_base + blockIdx.z;
  int count = cnt[e];
  int m0 = blockIdx.y * 128;
  if (m0 >= count) return;                  // early-exit worst-case tiles
  int nt = blockIdx.x;                      // a-cols [nt*64, nt*64+64)
  const bf16_t* W1e = W1t + (size_t)blockIdx.z * estride;

  __shared__ bf16_t As[128 * 64];
  __shared__ bf16_t Bs[128 * 64];
  __shared__ int   stok[128];
  __shared__ float sw[128];
  int tid = threadIdx.x;
  if (tid < 128) {
    int m = m0 + tid;
    stok[tid] = (m < count) ? tok_list[e * T_TOK + m] : 0;
    sw[tid]   = (m < count) ? w_list[e * T_TOK + m] : 0.f;
  }
  __syncthreads();

  int wave = tid >> 6, lane = tid & 63;
  int quad = lane >> 4, l16 = lane & 15;
  int rsub = lane >> 3, csub = lane & 7;

  size_t asrc[4]; const bf16_t* bsrc[4];
  bf16_t* aldst[4]; bf16_t* bldst[4];
  #pragma unroll
  for (int s = 0; s < 4; ++s) {
    int inst = wave * 4 + s;
    int row = inst * 8 + rsub;
    asrc[s] = (size_t)stok[row] * DMODEL + csub * 8;
    int grow = (row < 64) ? (nt * 64 + row) : (FF + nt * 64 + (row - 64)); // a / g halves
    bsrc[s] = W1e + (size_t)grow * DMODEL + csub * 8;
    aldst[s] = As + inst * 512;
    bldst[s] = Bs + inst * 512;
  }

  f32x4 acc[2][8];
  #pragma unroll
  for (int i = 0; i < 2; ++i)
    #pragma unroll
    for (int j = 0; j < 8; ++j) acc[i][j] = (f32x4){0.f, 0.f, 0.f, 0.f};

  for (int k0 = 0; k0 < DMODEL; k0 += 64) {
    __syncthreads();
    #pragma unroll
    for (int s = 0; s < 4; ++s) {
      gload_lds16(xb + asrc[s] + k0, aldst[s]);
      gload_lds16(bsrc[s] + k0, bldst[s]);
    }
    __syncthreads();
    #pragma unroll
    for (int kh = 0; kh < 2; ++kh) {
      bf16x8 a0 = *(const bf16x8*)&As[(wave * 32      + l16) * 64 + kh * 32 + quad * 8];
      bf16x8 a1 = *(const bf16x8*)&As[(wave * 32 + 16 + l16) * 64 + kh * 32 + quad * 8];
      #pragma unroll
      for (int j = 0; j < 8; ++j) {
        bf16x8 b = *(const bf16x8*)&Bs[(j * 16 + l16) * 64 + kh * 32 + quad * 8];
        acc[0][j] = __builtin_amdgcn_mfma_f32_16x16x32_bf16(a0, b, acc[0][j], 0, 0, 0);
        acc[1][j] = __builtin_amdgcn_mfma_f32_16x16x32_bf16(a1, b, acc[1][j], 0, 0, 0);
      }
    }
  }

  int uoff = offs[e];
  const float* b1e = b1 + (size_t)e * FF2;
  #pragma unroll
  for (int j = 0; j < 4; ++j) {              // col-frags j (a) pair with j+4 (g)
    int f = nt * 64 + j * 16 + l16;
    float ba = b1e[f];
    float bg = b1e[FF + f];
    #pragma unroll
    for (int i = 0; i < 2; ++i) {
      f32x4 av = acc[i][j];
      f32x4 gv = acc[i][j + 4];
      #pragma unroll
      for (int r = 0; r < 4; ++r) {
        int m = wave * 32 + i * 16 + quad * 4 + r;   // C-frag: row=quad*4+reg, col=lane&15
        if (m0 + m < count) {
          float aa = av[r] + ba;
          float gg = gv[r] + bg;
          float u = sw[m] * aa * gg / (1.f + expf(-gg));   // w * a * silu(g)
          U[(size_t)(uoff + m0 + m) * FF + f] = (bf16_t)u;
        }
      }
    }
  }
}

// ---------------- GEMM2: U segment * W2t[e] -> atomicAdd scatter into out
__global__ __launch_bounds__(256) void moe_gemm2(
    const bf16_t* __restrict__ U, const bf16_t* __restrict__ W2t,
    const int* __restrict__ cnt, const int* __restrict__ offs,
    const int* __restrict__ tok_list, float* __restrict__ out,
    int e_base, long estride)
{
  int e = e_base + blockIdx.z;
  int count = cnt[e];
  int m0 = blockIdx.y * 128;
  if (m0 >= count) return;
  int n0 = blockIdx.x * 128;
  const bf16_t* W2e = W2t + (size_t)blockIdx.z * estride;

  __shared__ bf16_t As[128 * 64];
  __shared__ bf16_t Bs[128 * 64];
  __shared__ int stok[128];
  int tid = threadIdx.x;
  if (tid < 128) {
    int m = m0 + tid;
    stok[tid] = (m < count) ? tok_list[e * T_TOK + m] : 0;
  }
  int wave = tid >> 6, lane = tid & 63;
  int quad = lane >> 4, l16 = lane & 15;
  int rsub = lane >> 3, csub = lane & 7;
  int uoff = offs[e];

  const bf16_t* asrc[4]; const bf16_t* bsrc[4];
  bf16_t* aldst[4]; bf16_t* bldst[4];
  #pragma unroll
  for (int s = 0; s < 4; ++s) {
    int inst = wave * 4 + s;
    int row = inst * 8 + rsub;
    asrc[s] = U   + (size_t)(uoff + m0 + row) * FF + csub * 8;  // U padded +128 rows
    bsrc[s] = W2e + (size_t)(n0 + row)        * FF + csub * 8;
    aldst[s] = As + inst * 512;
    bldst[s] = Bs + inst * 512;
  }

  f32x4 acc[2][8];
  #pragma unroll
  for (int i = 0; i < 2; ++i)
    #pragma unroll
    for (int j = 0; j < 8; ++j) acc[i][j] = (f32x4){0.f, 0.f, 0.f, 0.f};

  for (int k0 = 0; k0 < FF; k0 += 64) {
    __syncthreads();
    #pragma unroll
    for (int s = 0; s < 4; ++s) {
      gload_lds16(asrc[s] + k0, aldst[s]);
      gload_lds16(bsrc[s] + k0, bldst[s]);
    }
    __syncthreads();
    #pragma unroll
    for (int kh = 0; kh < 2; ++kh) {
      bf16x8 a0 = *(const bf16x8*)&As[(wave * 32      + l16) * 64 + kh * 32 + quad * 8];
      bf16x8 a1 = *(const bf16x8*)&As[(wave * 32 + 16 + l16) * 64 + kh * 32 + quad * 8];
      #pragma unroll
      for (int j = 0; j < 8; ++j) {
        bf16x8 b = *(const bf16x8*)&Bs[(j * 16 + l16) * 64 + kh * 32 + quad * 8];
        acc[0][j] = __builtin_amdgcn_mfma_f32_16x16x32_bf16(a0, b, acc[0][j], 0, 0, 0);
        acc[1][j] = __builtin_amdgcn_mfma_f32_16x16x32_bf16(a1, b, acc[1][j], 0, 0, 0);
      }
    }
  }

  #pragma unroll
  for (int j = 0; j < 8; ++j) {
    int n = n0 + j * 16 + l16;
    #pragma unroll
    for (int i = 0; i < 2; ++i) {
      f32x4 av = acc[i][j];
      #pragma unroll
      for (int r = 0; r < 4; ++r) {
        int m = wave * 32 + i * 16 + quad * 4 + r;
        if (m0 + m < count)
          atomicAdd(&out[(size_t)stok[m] * DMODEL + n], av[r]);
      }
    }
  }
}

extern "C" void kernel_launch(void* const* d_in, const int* in_sizes, int n_in,
                              void* d_out, int out_size, void* d_ws, size_t ws_size,
                              hipStream_t stream)
{
  const float* x    = (const float*)d_in[0];
  const float* Wr   = (const float*)d_in[1];
  const float* temp = (const float*)d_in[2];
  const float* W1   = (const float*)d_in[3];
  const float* b1   = (const float*)d_in[4];
  const float* W2   = (const float*)d_in[5];
  const float* b2   = (const float*)d_in[6];
  float* out = (float*)d_out;

  char* ws = (char*)d_ws;
  size_t off = 0;
  auto alloc = [&](size_t b) { void* p = ws + off; off += (b + 255) & ~(size_t)255; return p; };
  bf16_t* xb  = (bf16_t*)alloc((size_t)T_TOK * DMODEL * 2);
  bf16_t* U   = (bf16_t*)alloc((size_t)(2 * T_TOK + 128) * FF * 2);  // +128 row pad for tile overread
  int*   cnt  = (int*)alloc(256);
  int*   offs = (int*)alloc(256);
  int*   tok  = (int*)alloc((size_t)NEXP * T_TOK * 4);
  float* wl   = (float*)alloc((size_t)NEXP * T_TOK * 4);
  size_t base = off;
  const size_t W1T_FULL = (size_t)NEXP * FF2 * DMODEL * 2;
  const size_t W2T_FULL = (size_t)NEXP * DMODEL * FF * 2;
  bool batched = (ws_size >= base + W1T_FULL + W2T_FULL);  // constant per process: graph-safe

  hipMemsetAsync(cnt, 0, NEXP * sizeof(int), stream);
  moe_router<<<dim3(T_TOK / 4), dim3(256), 0, stream>>>(x, Wr, temp, b2, xb, out, cnt, tok, wl);
  moe_prefix<<<dim3(1), dim3(64), 0, stream>>>(cnt, offs);

  if (batched) {
    bf16_t* W1t = (bf16_t*)alloc(W1T_FULL);
    bf16_t* W2t = (bf16_t*)alloc(W2T_FULL);
    tcast64<<<dim3(FF2 / 64, DMODEL / 64, NEXP), dim3(256), 0, stream>>>(W1, W1t, DMODEL, FF2);
    tcast64<<<dim3(DMODEL / 64, FF / 64, NEXP), dim3(256), 0, stream>>>(W2, W2t, FF, DMODEL);
    moe_gemm1<<<dim3(FF / 64, T_TOK / 128, NEXP), dim3(256), 0, stream>>>(
        xb, W1t, b1, cnt, offs, tok, wl, U, 0, (long)FF2 * DMODEL);
    moe_gemm2<<<dim3(DMODEL / 128, T_TOK / 128, NEXP), dim3(256), 0, stream>>>(
        U, W2t, cnt, offs, tok, out, 0, (long)DMODEL * FF);
  } else {
    // ws too small for all transposed weights: rotate one-expert buffers (stream-serial)
    bf16_t* W1t = (bf16_t*)alloc((size_t)FF2 * DMODEL * 2);
    bf16_t* W2t = (bf16_t*)alloc((size_t)DMODEL * FF * 2);
    for (int e = 0; e < NEXP; ++e) {
      tcast64<<<dim3(FF2 / 64, DMODEL / 64, 1), dim3(256), 0, stream>>>(
          W1 + (size_t)e * DMODEL * FF2, W1t, DMODEL, FF2);
      moe_gemm1<<<dim3(FF / 64, T_TOK / 128, 1), dim3(256), 0, stream>>>(
          xb, W1t, b1, cnt, offs, tok, wl, U, e, 0);
    }
    for (int e = 0; e < NEXP; ++e) {
      tcast64<<<dim3(DMODEL / 64, FF / 64, 1), dim3(256), 0, stream>>>(
          W2 + (size_t)e * FF * DMODEL, W2t, FF, DMODEL);
      moe_gemm2<<<dim3(DMODEL / 128, T_TOK / 128, 1), dim3(256), 0, stream>>>(
          U, W2t, cnt, offs, tok, out, e, 0);
    }
  }
}

// Round 2
// 582.019 us; speedup vs baseline: 1.0512x; 1.0512x over previous
//
#include <hip/hip_runtime.h>
#include <hip/hip_bf16.h>
#include <math.h>

// MoE top-2 of 8 experts, D=1024, FF=2048 (SwiGLU), T=4096 tokens.
// Pipeline: router(+x cast,+b2 init) -> prefix -> transpose-cast weights ->
// GEMM1 (gather A, fused SwiGLU*w -> U bf16) -> GEMM2 (atomicAdd scatter).
// R2: XOR-swizzled LDS layout in both GEMMs (kills 8-way bank conflicts:
//     row stride was 128 B = 32 banks exactly). Store row r chunk c at
//     position c^(r&7); staging permutes per-lane global src chunk instead
//     of the (hardwired) global_load_lds dst.

#define T_TOK  4096
#define DMODEL 1024
#define NEXP   8
#define FF     2048
#define FF2    4096

typedef __bf16 bf16_t;
typedef bf16_t bf16x8 __attribute__((ext_vector_type(8)));
typedef float  f32x4  __attribute__((ext_vector_type(4)));

__device__ __forceinline__ void gload_lds16(const void* g, void* l) {
  __builtin_amdgcn_global_load_lds((const __attribute__((address_space(1))) void*)g,
                                   (__attribute__((address_space(3))) void*)l, 16, 0, 0);
}

// ---------------- router: logits, top-2 softmax, bucket-append, x->bf16, out=sum w*b2
__global__ __launch_bounds__(256) void moe_router(
    const float* __restrict__ x, const float* __restrict__ Wr,
    const float* __restrict__ temp, const float* __restrict__ b2,
    bf16_t* __restrict__ xb, float* __restrict__ out,
    int* __restrict__ cnt, int* __restrict__ tok_list, float* __restrict__ w_list)
{
  __shared__ float sWr[DMODEL * NEXP];   // 32 KB, whole router weight
  for (int i = threadIdx.x; i < DMODEL * NEXP; i += 256) sWr[i] = Wr[i];
  __syncthreads();

  int wave = threadIdx.x >> 6, lane = threadIdx.x & 63;
  int t = blockIdx.x * 4 + wave;
  const float* xr = x + (size_t)t * DMODEL;

  f32x4 acc0 = {0.f, 0.f, 0.f, 0.f}, acc1 = {0.f, 0.f, 0.f, 0.f};
  #pragma unroll
  for (int i = 0; i < 16; ++i) {
    int d = lane + 64 * i;                    // coalesced
    float v = xr[d];
    xb[(size_t)t * DMODEL + d] = (bf16_t)v;   // fused cast
    const f32x4* wr = (const f32x4*)&sWr[d * NEXP];
    acc0 += v * wr[0];
    acc1 += v * wr[1];
  }
  #pragma unroll
  for (int off = 32; off; off >>= 1) {
    #pragma unroll
    for (int q = 0; q < 4; ++q) {
      acc0[q] += __shfl_down(acc0[q], off, 64);
      acc1[q] += __shfl_down(acc1[q], off, 64);
    }
  }
  int bi = 0, si = 0; float wb = 0.f, wsc = 0.f;
  if (lane == 0) {
    float invt = 1.f / temp[0];
    float lg[NEXP] = {acc0[0], acc0[1], acc0[2], acc0[3],
                      acc1[0], acc1[1], acc1[2], acc1[3]};
    float best = -3.4e38f, sec = -3.4e38f;
    #pragma unroll
    for (int e = 0; e < NEXP; ++e) {
      float l = lg[e] * invt;
      if (l > best)     { sec = best; si = bi; best = l; bi = e; }
      else if (l > sec) { sec = l; si = e; }
    }
    float ex = expf(sec - best);          // top-2 softmax
    wb  = 1.f / (1.f + ex);
    wsc = ex  / (1.f + ex);
    int p0 = atomicAdd(&cnt[bi], 1);
    tok_list[bi * T_TOK + p0] = t; w_list[bi * T_TOK + p0] = wb;
    int p1 = atomicAdd(&cnt[si], 1);
    tok_list[si * T_TOK + p1] = t; w_list[si * T_TOK + p1] = wsc;
  }
  bi  = __shfl(bi, 0, 64);  si  = __shfl(si, 0, 64);
  wb  = __shfl(wb, 0, 64);  wsc = __shfl(wsc, 0, 64);
  const float* b2a = b2 + (size_t)bi * DMODEL;
  const float* b2b = b2 + (size_t)si * DMODEL;
  float* orow = out + (size_t)t * DMODEL;
  #pragma unroll
  for (int i = 0; i < 16; ++i) {
    int d = lane + 64 * i;
    orow[d] = wb * b2a[d] + wsc * b2b[d];   // init out with weighted b2
  }
}

__global__ void moe_prefix(const int* __restrict__ cnt, int* __restrict__ offs) {
  if (threadIdx.x == 0) {
    int s = 0;
    for (int e = 0; e < NEXP; ++e) { offs[e] = s; s += cnt[e]; }
    offs[NEXP] = s;
  }
}

// ---------------- transpose-cast: fp32 [R][C] -> bf16 [C][R], per blockIdx.z slice
__global__ __launch_bounds__(256) void tcast64(
    const float* __restrict__ in, bf16_t* __restrict__ outp, int R, int C)
{
  __shared__ float tile[64][65];            // +1 pad: conflict-free transpose
  const float* inp = in + (size_t)blockIdx.z * R * C;
  bf16_t* op = outp + (size_t)blockIdx.z * R * C;
  int c0 = blockIdx.x * 64, r0 = blockIdx.y * 64;
  int tx = threadIdx.x & 63, ty = threadIdx.x >> 6;
  #pragma unroll
  for (int j = 0; j < 64; j += 4)
    tile[ty + j][tx] = inp[(size_t)(r0 + ty + j) * C + c0 + tx];
  __syncthreads();
  #pragma unroll
  for (int j = 0; j < 64; j += 4)
    op[(size_t)(c0 + ty + j) * R + r0 + tx] = (bf16_t)tile[tx][ty + j];
}

// ---------------- GEMM1: gathered x rows [cnt x 1024] * W1t[e] -> SwiGLU*w -> U bf16
// Block: 128 rows x (64 a-cols + 64 g-cols). 4 waves of 32 rows x 128 cols.
__global__ __launch_bounds__(256) void moe_gemm1(
    const bf16_t* __restrict__ xb, const bf16_t* __restrict__ W1t,
    const float* __restrict__ b1, const int* __restrict__ cnt,
    const int* __restrict__ offs, const int* __restrict__ tok_list,
    const float* __restrict__ w_list, bf16_t* __restrict__ U,
    int e_base, long estride)
{
  int e = e_base + blockIdx.z;
  int count = cnt[e];
  int m0 = blockIdx.y * 128;
  if (m0 >= count) return;                  // early-exit worst-case tiles
  int nt = blockIdx.x;                      // a-cols [nt*64, nt*64+64)
  const bf16_t* W1e = W1t + (size_t)blockIdx.z * estride;

  __shared__ bf16_t As[128 * 64];
  __shared__ bf16_t Bs[128 * 64];
  __shared__ int   stok[128];
  __shared__ float sw[128];
  int tid = threadIdx.x;
  if (tid < 128) {
    int m = m0 + tid;
    stok[tid] = (m < count) ? tok_list[e * T_TOK + m] : 0;
    sw[tid]   = (m < count) ? w_list[e * T_TOK + m] : 0.f;
  }
  __syncthreads();

  int wave = tid >> 6, lane = tid & 63;
  int quad = lane >> 4, l16 = lane & 15;
  int rsub = lane >> 3;
  int swz  = (lane & 7) ^ rsub;             // XOR-swizzled global src chunk

  size_t asrc[4]; const bf16_t* bsrc[4];
  bf16_t* aldst[4]; bf16_t* bldst[4];
  #pragma unroll
  for (int s = 0; s < 4; ++s) {
    int inst = wave * 4 + s;
    int row = inst * 8 + rsub;              // row&7 == rsub
    asrc[s] = (size_t)stok[row] * DMODEL + swz * 8;
    int grow = (row < 64) ? (nt * 64 + row) : (FF + nt * 64 + (row - 64)); // a / g halves
    bsrc[s] = W1e + (size_t)grow * DMODEL + swz * 8;
    aldst[s] = As + inst * 512;
    bldst[s] = Bs + inst * 512;
  }

  f32x4 acc[2][8];
  #pragma unroll
  for (int i = 0; i < 2; ++i)
    #pragma unroll
    for (int j = 0; j < 8; ++j) acc[i][j] = (f32x4){0.f, 0.f, 0.f, 0.f};

  for (int k0 = 0; k0 < DMODEL; k0 += 64) {
    __syncthreads();
    #pragma unroll
    for (int s = 0; s < 4; ++s) {
      gload_lds16(xb + asrc[s] + k0, aldst[s]);
      gload_lds16(bsrc[s] + k0, bldst[s]);
    }
    __syncthreads();
    #pragma unroll
    for (int kh = 0; kh < 2; ++kh) {
      int so = ((kh * 4 + quad) ^ (l16 & 7)) * 8;   // swizzled chunk offset
      bf16x8 a0 = *(const bf16x8*)&As[(wave * 32      + l16) * 64 + so];
      bf16x8 a1 = *(const bf16x8*)&As[(wave * 32 + 16 + l16) * 64 + so];
      #pragma unroll
      for (int j = 0; j < 8; ++j) {
        bf16x8 b = *(const bf16x8*)&Bs[(j * 16 + l16) * 64 + so];
        acc[0][j] = __builtin_amdgcn_mfma_f32_16x16x32_bf16(a0, b, acc[0][j], 0, 0, 0);
        acc[1][j] = __builtin_amdgcn_mfma_f32_16x16x32_bf16(a1, b, acc[1][j], 0, 0, 0);
      }
    }
  }

  int uoff = offs[e];
  const float* b1e = b1 + (size_t)e * FF2;
  #pragma unroll
  for (int j = 0; j < 4; ++j) {              // col-frags j (a) pair with j+4 (g)
    int f = nt * 64 + j * 16 + l16;
    float ba = b1e[f];
    float bg = b1e[FF + f];
    #pragma unroll
    for (int i = 0; i < 2; ++i) {
      f32x4 av = acc[i][j];
      f32x4 gv = acc[i][j + 4];
      #pragma unroll
      for (int r = 0; r < 4; ++r) {
        int m = wave * 32 + i * 16 + quad * 4 + r;   // C-frag: row=quad*4+reg, col=lane&15
        if (m0 + m < count) {
          float aa = av[r] + ba;
          float gg = gv[r] + bg;
          float u = sw[m] * aa * gg / (1.f + __expf(-gg));   // w * a * silu(g)
          U[(size_t)(uoff + m0 + m) * FF + f] = (bf16_t)u;
        }
      }
    }
  }
}

// ---------------- GEMM2: U segment * W2t[e] -> atomicAdd scatter into out
__global__ __launch_bounds__(256) void moe_gemm2(
    const bf16_t* __restrict__ U, const bf16_t* __restrict__ W2t,
    const int* __restrict__ cnt, const int* __restrict__ offs,
    const int* __restrict__ tok_list, float* __restrict__ out,
    int e_base, long estride)
{
  int e = e_base + blockIdx.z;
  int count = cnt[e];
  int m0 = blockIdx.y * 128;
  if (m0 >= count) return;
  int n0 = blockIdx.x * 128;
  const bf16_t* W2e = W2t + (size_t)blockIdx.z * estride;

  __shared__ bf16_t As[128 * 64];
  __shared__ bf16_t Bs[128 * 64];
  __shared__ int stok[128];
  int tid = threadIdx.x;
  if (tid < 128) {
    int m = m0 + tid;
    stok[tid] = (m < count) ? tok_list[e * T_TOK + m] : 0;
  }
  int wave = tid >> 6, lane = tid & 63;
  int quad = lane >> 4, l16 = lane & 15;
  int rsub = lane >> 3;
  int swz  = (lane & 7) ^ rsub;             // XOR-swizzled global src chunk
  int uoff = offs[e];

  const bf16_t* asrc[4]; const bf16_t* bsrc[4];
  bf16_t* aldst[4]; bf16_t* bldst[4];
  #pragma unroll
  for (int s = 0; s < 4; ++s) {
    int inst = wave * 4 + s;
    int row = inst * 8 + rsub;
    asrc[s] = U   + (size_t)(uoff + m0 + row) * FF + swz * 8;  // U padded +128 rows
    bsrc[s] = W2e + (size_t)(n0 + row)        * FF + swz * 8;
    aldst[s] = As + inst * 512;
    bldst[s] = Bs + inst * 512;
  }

  f32x4 acc[2][8];
  #pragma unroll
  for (int i = 0; i < 2; ++i)
    #pragma unroll
    for (int j = 0; j < 8; ++j) acc[i][j] = (f32x4){0.f, 0.f, 0.f, 0.f};

  for (int k0 = 0; k0 < FF; k0 += 64) {
    __syncthreads();
    #pragma unroll
    for (int s = 0; s < 4; ++s) {
      gload_lds16(asrc[s] + k0, aldst[s]);
      gload_lds16(bsrc[s] + k0, bldst[s]);
    }
    __syncthreads();
    #pragma unroll
    for (int kh = 0; kh < 2; ++kh) {
      int so = ((kh * 4 + quad) ^ (l16 & 7)) * 8;   // swizzled chunk offset
      bf16x8 a0 = *(const bf16x8*)&As[(wave * 32      + l16) * 64 + so];
      bf16x8 a1 = *(const bf16x8*)&As[(wave * 32 + 16 + l16) * 64 + so];
      #pragma unroll
      for (int j = 0; j < 8; ++j) {
        bf16x8 b = *(const bf16x8*)&Bs[(j * 16 + l16) * 64 + so];
        acc[0][j] = __builtin_amdgcn_mfma_f32_16x16x32_bf16(a0, b, acc[0][j], 0, 0, 0);
        acc[1][j] = __builtin_amdgcn_mfma_f32_16x16x32_bf16(a1, b, acc[1][j], 0, 0, 0);
      }
    }
  }

  #pragma unroll
  for (int j = 0; j < 8; ++j) {
    int n = n0 + j * 16 + l16;
    #pragma unroll
    for (int i = 0; i < 2; ++i) {
      f32x4 av = acc[i][j];
      #pragma unroll
      for (int r = 0; r < 4; ++r) {
        int m = wave * 32 + i * 16 + quad * 4 + r;
        if (m0 + m < count)
          atomicAdd(&out[(size_t)stok[m] * DMODEL + n], av[r]);
      }
    }
  }
}

extern "C" void kernel_launch(void* const* d_in, const int* in_sizes, int n_in,
                              void* d_out, int out_size, void* d_ws, size_t ws_size,
                              hipStream_t stream)
{
  const float* x    = (const float*)d_in[0];
  const float* Wr   = (const float*)d_in[1];
  const float* temp = (const float*)d_in[2];
  const float* W1   = (const float*)d_in[3];
  const float* b1   = (const float*)d_in[4];
  const float* W2   = (const float*)d_in[5];
  const float* b2   = (const float*)d_in[6];
  float* out = (float*)d_out;

  char* ws = (char*)d_ws;
  size_t off = 0;
  auto alloc = [&](size_t b) { void* p = ws + off; off += (b + 255) & ~(size_t)255; return p; };
  bf16_t* xb  = (bf16_t*)alloc((size_t)T_TOK * DMODEL * 2);
  bf16_t* U   = (bf16_t*)alloc((size_t)(2 * T_TOK + 128) * FF * 2);  // +128 row pad for tile overread
  int*   cnt  = (int*)alloc(256);
  int*   offs = (int*)alloc(256);
  int*   tok  = (int*)alloc((size_t)NEXP * T_TOK * 4);
  float* wl   = (float*)alloc((size_t)NEXP * T_TOK * 4);
  size_t base = off;
  const size_t W1T_FULL = (size_t)NEXP * FF2 * DMODEL * 2;
  const size_t W2T_FULL = (size_t)NEXP * DMODEL * FF * 2;
  bool batched = (ws_size >= base + W1T_FULL + W2T_FULL);  // constant per process: graph-safe

  hipMemsetAsync(cnt, 0, NEXP * sizeof(int), stream);
  moe_router<<<dim3(T_TOK / 4), dim3(256), 0, stream>>>(x, Wr, temp, b2, xb, out, cnt, tok, wl);
  moe_prefix<<<dim3(1), dim3(64), 0, stream>>>(cnt, offs);

  if (batched) {
    bf16_t* W1t = (bf16_t*)alloc(W1T_FULL);
    bf16_t* W2t = (bf16_t*)alloc(W2T_FULL);
    tcast64<<<dim3(FF2 / 64, DMODEL / 64, NEXP), dim3(256), 0, stream>>>(W1, W1t, DMODEL, FF2);
    tcast64<<<dim3(DMODEL / 64, FF / 64, NEXP), dim3(256), 0, stream>>>(W2, W2t, FF, DMODEL);
    moe_gemm1<<<dim3(FF / 64, T_TOK / 128, NEXP), dim3(256), 0, stream>>>(
        xb, W1t, b1, cnt, offs, tok, wl, U, 0, (long)FF2 * DMODEL);
    moe_gemm2<<<dim3(DMODEL / 128, T_TOK / 128, NEXP), dim3(256), 0, stream>>>(
        U, W2t, cnt, offs, tok, out, 0, (long)DMODEL * FF);
  } else {
    // ws too small for all transposed weights: rotate one-expert buffers (stream-serial)
    bf16_t* W1t = (bf16_t*)alloc((size_t)FF2 * DMODEL * 2);
    bf16_t* W2t = (bf16_t*)alloc((size_t)DMODEL * FF * 2);
    for (int e = 0; e < NEXP; ++e) {
      tcast64<<<dim3(FF2 / 64, DMODEL / 64, 1), dim3(256), 0, stream>>>(
          W1 + (size_t)e * DMODEL * FF2, W1t, DMODEL, FF2);
      moe_gemm1<<<dim3(FF / 64, T_TOK / 128, 1), dim3(256), 0, stream>>>(
          xb, W1t, b1, cnt, offs, tok, wl, U, e, 0);
    }
    for (int e = 0; e < NEXP; ++e) {
      tcast64<<<dim3(DMODEL / 64, FF / 64, 1), dim3(256), 0, stream>>>(
          W2 + (size_t)e * FF * DMODEL, W2t, FF, DMODEL);
      moe_gemm2<<<dim3(DMODEL / 128, T_TOK / 128, 1), dim3(256), 0, stream>>>(
          U, W2t, cnt, offs, tok, out, e, 0);
    }
  }
}

// Round 3
// 538.881 us; speedup vs baseline: 1.1354x; 1.0801x over previous
//
#include <hip/hip_runtime.h>
#include <hip/hip_bf16.h>
#include <math.h>

// MoE top-2 of 8 experts, D=1024, FF=2048 (SwiGLU), T=4096 tokens.
// Pipeline: router(+x cast) -> prefix -> tcast_fast weights -> GEMM1
// (gather A, fused SwiGLU*w -> U bf16) -> GEMM2 (plain stores -> Y) ->
// combine (Y rows + weighted b2 -> out).
// R2: XOR-swizzled LDS in GEMMs (bank conflicts 3.3e7 -> 0).
// R3: vectorized transpose-cast (float4 in / bf16x8 out, was 2 B/lane
//     stores ~190us); GEMM2 atomicAdd -> plain stores to pair-rows Y +
//     combine kernel (atomic RMW contention removed, deterministic).

#define T_TOK  4096
#define DMODEL 1024
#define NEXP   8
#define FF     2048
#define FF2    4096

typedef __bf16 bf16_t;
typedef bf16_t bf16x8 __attribute__((ext_vector_type(8)));
typedef float  f32x4  __attribute__((ext_vector_type(4)));

__device__ __forceinline__ void gload_lds16(const void* g, void* l) {
  __builtin_amdgcn_global_load_lds((const __attribute__((address_space(1))) void*)g,
                                   (__attribute__((address_space(3))) void*)l, 16, 0, 0);
}

// ---------------- router: logits, top-2 softmax, bucket-append, x->bf16, slot map
__global__ __launch_bounds__(256) void moe_router(
    const float* __restrict__ x, const float* __restrict__ Wr,
    const float* __restrict__ temp,
    bf16_t* __restrict__ xb,
    int* __restrict__ cnt, int* __restrict__ tok_list, float* __restrict__ w_list,
    int* __restrict__ slot)
{
  __shared__ float sWr[DMODEL * NEXP];   // 32 KB, whole router weight
  for (int i = threadIdx.x; i < DMODEL * NEXP; i += 256) sWr[i] = Wr[i];
  __syncthreads();

  int wave = threadIdx.x >> 6, lane = threadIdx.x & 63;
  int t = blockIdx.x * 4 + wave;
  const float* xr = x + (size_t)t * DMODEL;

  f32x4 acc0 = {0.f, 0.f, 0.f, 0.f}, acc1 = {0.f, 0.f, 0.f, 0.f};
  #pragma unroll
  for (int i = 0; i < 16; ++i) {
    int d = lane + 64 * i;                    // coalesced
    float v = xr[d];
    xb[(size_t)t * DMODEL + d] = (bf16_t)v;   // fused cast
    const f32x4* wr = (const f32x4*)&sWr[d * NEXP];
    acc0 += v * wr[0];
    acc1 += v * wr[1];
  }
  #pragma unroll
  for (int off = 32; off; off >>= 1) {
    #pragma unroll
    for (int q = 0; q < 4; ++q) {
      acc0[q] += __shfl_down(acc0[q], off, 64);
      acc1[q] += __shfl_down(acc1[q], off, 64);
    }
  }
  if (lane == 0) {
    float invt = 1.f / temp[0];
    float lg[NEXP] = {acc0[0], acc0[1], acc0[2], acc0[3],
                      acc1[0], acc1[1], acc1[2], acc1[3]};
    int bi = 0, si = 0;
    float best = -3.4e38f, sec = -3.4e38f;
    #pragma unroll
    for (int e = 0; e < NEXP; ++e) {
      float l = lg[e] * invt;
      if (l > best)     { sec = best; si = bi; best = l; bi = e; }
      else if (l > sec) { sec = l; si = e; }
    }
    float ex = expf(sec - best);          // top-2 softmax
    float wb  = 1.f / (1.f + ex);
    float wsc = ex  / (1.f + ex);
    int p0 = atomicAdd(&cnt[bi], 1);
    tok_list[bi * T_TOK + p0] = t; w_list[bi * T_TOK + p0] = wb;
    int p1 = atomicAdd(&cnt[si], 1);
    tok_list[si * T_TOK + p1] = t; w_list[si * T_TOK + p1] = wsc;
    slot[2 * t]     = bi * T_TOK + p0;    // expert = v>>12, pos = v&4095
    slot[2 * t + 1] = si * T_TOK + p1;
  }
}

__global__ void moe_prefix(const int* __restrict__ cnt, int* __restrict__ offs) {
  if (threadIdx.x == 0) {
    int s = 0;
    for (int e = 0; e < NEXP; ++e) { offs[e] = s; s += cnt[e]; }
    offs[NEXP] = s;
  }
}

// ---------------- transpose-cast: fp32 [R][C] -> bf16 [C][R], vectorized.
// float4 global loads -> tile[64][65] (2-way max on both LDS phases) ->
// 8 scalar LDS reads -> bf16x8 16-B global stores.
__global__ __launch_bounds__(256) void tcast_fast(
    const float* __restrict__ in, bf16_t* __restrict__ outp, int R, int C)
{
  __shared__ float tile[64][65];
  const float* inp = in + (size_t)blockIdx.z * R * C;
  bf16_t* op = outp + (size_t)blockIdx.z * R * C;
  int c0 = blockIdx.x * 64, r0 = blockIdx.y * 64;
  int tid = threadIdx.x;
  int lr = tid >> 4;            // 0..15
  int lc4 = (tid & 15) * 4;     // 0,4,..,60
  #pragma unroll
  for (int p = 0; p < 4; ++p) {
    int r = p * 16 + lr;
    const float4 v = *(const float4*)&inp[(size_t)(r0 + r) * C + c0 + lc4];
    tile[r][lc4 + 0] = v.x; tile[r][lc4 + 1] = v.y;
    tile[r][lc4 + 2] = v.z; tile[r][lc4 + 3] = v.w;
  }
  __syncthreads();
  int rr8 = (tid & 7) * 8;
  #pragma unroll
  for (int it = 0; it < 2; ++it) {
    int cc = (tid >> 3) + it * 32;
    bf16x8 o;
    #pragma unroll
    for (int j = 0; j < 8; ++j) o[j] = (bf16_t)tile[rr8 + j][cc];
    *(bf16x8*)&op[(size_t)(c0 + cc) * R + r0 + rr8] = o;
  }
}

// ---------------- GEMM1: gathered x rows [cnt x 1024] * W1t[e] -> SwiGLU*w -> U bf16
// Block: 128 rows x (64 a-cols + 64 g-cols). 4 waves of 32 rows x 128 cols.
__global__ __launch_bounds__(256) void moe_gemm1(
    const bf16_t* __restrict__ xb, const bf16_t* __restrict__ W1t,
    const float* __restrict__ b1, const int* __restrict__ cnt,
    const int* __restrict__ offs, const int* __restrict__ tok_list,
    const float* __restrict__ w_list, bf16_t* __restrict__ U,
    int e_base, long estride)
{
  int e = e_base + blockIdx.z;
  int count = cnt[e];
  int m0 = blockIdx.y * 128;
  if (m0 >= count) return;                  // early-exit worst-case tiles
  int nt = blockIdx.x;                      // a-cols [nt*64, nt*64+64)
  const bf16_t* W1e = W1t + (size_t)blockIdx.z * estride;

  __shared__ bf16_t As[128 * 64];
  __shared__ bf16_t Bs[128 * 64];
  __shared__ int   stok[128];
  __shared__ float sw[128];
  int tid = threadIdx.x;
  if (tid < 128) {
    int m = m0 + tid;
    stok[tid] = (m < count) ? tok_list[e * T_TOK + m] : 0;
    sw[tid]   = (m < count) ? w_list[e * T_TOK + m] : 0.f;
  }
  __syncthreads();

  int wave = tid >> 6, lane = tid & 63;
  int quad = lane >> 4, l16 = lane & 15;
  int rsub = lane >> 3;
  int swz  = (lane & 7) ^ rsub;             // XOR-swizzled global src chunk

  size_t asrc[4]; const bf16_t* bsrc[4];
  bf16_t* aldst[4]; bf16_t* bldst[4];
  #pragma unroll
  for (int s = 0; s < 4; ++s) {
    int inst = wave * 4 + s;
    int row = inst * 8 + rsub;              // row&7 == rsub
    asrc[s] = (size_t)stok[row] * DMODEL + swz * 8;
    int grow = (row < 64) ? (nt * 64 + row) : (FF + nt * 64 + (row - 64)); // a / g halves
    bsrc[s] = W1e + (size_t)grow * DMODEL + swz * 8;
    aldst[s] = As + inst * 512;
    bldst[s] = Bs + inst * 512;
  }

  f32x4 acc[2][8];
  #pragma unroll
  for (int i = 0; i < 2; ++i)
    #pragma unroll
    for (int j = 0; j < 8; ++j) acc[i][j] = (f32x4){0.f, 0.f, 0.f, 0.f};

  for (int k0 = 0; k0 < DMODEL; k0 += 64) {
    __syncthreads();
    #pragma unroll
    for (int s = 0; s < 4; ++s) {
      gload_lds16(xb + asrc[s] + k0, aldst[s]);
      gload_lds16(bsrc[s] + k0, bldst[s]);
    }
    __syncthreads();
    #pragma unroll
    for (int kh = 0; kh < 2; ++kh) {
      int so = ((kh * 4 + quad) ^ (l16 & 7)) * 8;   // swizzled chunk offset
      bf16x8 a0 = *(const bf16x8*)&As[(wave * 32      + l16) * 64 + so];
      bf16x8 a1 = *(const bf16x8*)&As[(wave * 32 + 16 + l16) * 64 + so];
      #pragma unroll
      for (int j = 0; j < 8; ++j) {
        bf16x8 b = *(const bf16x8*)&Bs[(j * 16 + l16) * 64 + so];
        acc[0][j] = __builtin_amdgcn_mfma_f32_16x16x32_bf16(a0, b, acc[0][j], 0, 0, 0);
        acc[1][j] = __builtin_amdgcn_mfma_f32_16x16x32_bf16(a1, b, acc[1][j], 0, 0, 0);
      }
    }
  }

  int uoff = offs[e];
  const float* b1e = b1 + (size_t)e * FF2;
  #pragma unroll
  for (int j = 0; j < 4; ++j) {              // col-frags j (a) pair with j+4 (g)
    int f = nt * 64 + j * 16 + l16;
    float ba = b1e[f];
    float bg = b1e[FF + f];
    #pragma unroll
    for (int i = 0; i < 2; ++i) {
      f32x4 av = acc[i][j];
      f32x4 gv = acc[i][j + 4];
      #pragma unroll
      for (int r = 0; r < 4; ++r) {
        int m = wave * 32 + i * 16 + quad * 4 + r;   // C-frag: row=quad*4+reg, col=lane&15
        if (m0 + m < count) {
          float aa = av[r] + ba;
          float gg = gv[r] + bg;
          float u = sw[m] * aa * gg / (1.f + __expf(-gg));   // w * a * silu(g)
          U[(size_t)(uoff + m0 + m) * FF + f] = (bf16_t)u;
        }
      }
    }
  }
}

// ---------------- GEMM2: U segment * W2t[e] -> plain stores into Y pair-rows
__global__ __launch_bounds__(256) void moe_gemm2(
    const bf16_t* __restrict__ U, const bf16_t* __restrict__ W2t,
    const int* __restrict__ cnt, const int* __restrict__ offs,
    float* __restrict__ Y,
    int e_base, long estride)
{
  int e = e_base + blockIdx.z;
  int count = cnt[e];
  int m0 = blockIdx.y * 128;
  if (m0 >= count) return;
  int n0 = blockIdx.x * 128;
  const bf16_t* W2e = W2t + (size_t)blockIdx.z * estride;

  __shared__ bf16_t As[128 * 64];
  __shared__ bf16_t Bs[128 * 64];
  int tid = threadIdx.x;
  int wave = tid >> 6, lane = tid & 63;
  int quad = lane >> 4, l16 = lane & 15;
  int rsub = lane >> 3;
  int swz  = (lane & 7) ^ rsub;             // XOR-swizzled global src chunk
  int uoff = offs[e];

  const bf16_t* asrc[4]; const bf16_t* bsrc[4];
  bf16_t* aldst[4]; bf16_t* bldst[4];
  #pragma unroll
  for (int s = 0; s < 4; ++s) {
    int inst = wave * 4 + s;
    int row = inst * 8 + rsub;
    asrc[s] = U   + (size_t)(uoff + m0 + row) * FF + swz * 8;  // U padded +128 rows
    bsrc[s] = W2e + (size_t)(n0 + row)        * FF + swz * 8;
    aldst[s] = As + inst * 512;
    bldst[s] = Bs + inst * 512;
  }

  f32x4 acc[2][8];
  #pragma unroll
  for (int i = 0; i < 2; ++i)
    #pragma unroll
    for (int j = 0; j < 8; ++j) acc[i][j] = (f32x4){0.f, 0.f, 0.f, 0.f};

  for (int k0 = 0; k0 < FF; k0 += 64) {
    __syncthreads();
    #pragma unroll
    for (int s = 0; s < 4; ++s) {
      gload_lds16(asrc[s] + k0, aldst[s]);
      gload_lds16(bsrc[s] + k0, bldst[s]);
    }
    __syncthreads();
    #pragma unroll
    for (int kh = 0; kh < 2; ++kh) {
      int so = ((kh * 4 + quad) ^ (l16 & 7)) * 8;   // swizzled chunk offset
      bf16x8 a0 = *(const bf16x8*)&As[(wave * 32      + l16) * 64 + so];
      bf16x8 a1 = *(const bf16x8*)&As[(wave * 32 + 16 + l16) * 64 + so];
      #pragma unroll
      for (int j = 0; j < 8; ++j) {
        bf16x8 b = *(const bf16x8*)&Bs[(j * 16 + l16) * 64 + so];
        acc[0][j] = __builtin_amdgcn_mfma_f32_16x16x32_bf16(a0, b, acc[0][j], 0, 0, 0);
        acc[1][j] = __builtin_amdgcn_mfma_f32_16x16x32_bf16(a1, b, acc[1][j], 0, 0, 0);
      }
    }
  }

  #pragma unroll
  for (int j = 0; j < 8; ++j) {
    int n = n0 + j * 16 + l16;
    #pragma unroll
    for (int i = 0; i < 2; ++i) {
      f32x4 av = acc[i][j];
      #pragma unroll
      for (int r = 0; r < 4; ++r) {
        int m = wave * 32 + i * 16 + quad * 4 + r;
        if (m0 + m < count)
          Y[(size_t)(uoff + m0 + m) * DMODEL + n] = av[r];
      }
    }
  }
}

// ---------------- combine: out[t] = Y[row0] + Y[row1] + w0*b2[e0] + w1*b2[e1]
__global__ __launch_bounds__(256) void moe_combine(
    const float* __restrict__ Y, const float* __restrict__ b2,
    const int* __restrict__ slot, const float* __restrict__ w_list,
    const int* __restrict__ offs, float* __restrict__ out)
{
  int t = blockIdx.x;
  int v0 = slot[2 * t], v1 = slot[2 * t + 1];
  int e0 = v0 >> 12, p0 = v0 & (T_TOK - 1);
  int e1 = v1 >> 12, p1 = v1 & (T_TOK - 1);
  int r0 = offs[e0] + p0, r1 = offs[e1] + p1;
  float w0 = w_list[v0], w1 = w_list[v1];
  int d = threadIdx.x * 4;
  f32x4 y0 = *(const f32x4*)&Y[(size_t)r0 * DMODEL + d];
  f32x4 y1 = *(const f32x4*)&Y[(size_t)r1 * DMODEL + d];
  f32x4 c0 = *(const f32x4*)&b2[(size_t)e0 * DMODEL + d];
  f32x4 c1 = *(const f32x4*)&b2[(size_t)e1 * DMODEL + d];
  *(f32x4*)&out[(size_t)t * DMODEL + d] = y0 + y1 + w0 * c0 + w1 * c1;
}

extern "C" void kernel_launch(void* const* d_in, const int* in_sizes, int n_in,
                              void* d_out, int out_size, void* d_ws, size_t ws_size,
                              hipStream_t stream)
{
  const float* x    = (const float*)d_in[0];
  const float* Wr   = (const float*)d_in[1];
  const float* temp = (const float*)d_in[2];
  const float* W1   = (const float*)d_in[3];
  const float* b1   = (const float*)d_in[4];
  const float* W2   = (const float*)d_in[5];
  const float* b2   = (const float*)d_in[6];
  float* out = (float*)d_out;

  char* ws = (char*)d_ws;
  size_t off = 0;
  auto alloc = [&](size_t b) { void* p = ws + off; off += (b + 255) & ~(size_t)255; return p; };
  bf16_t* xb  = (bf16_t*)alloc((size_t)T_TOK * DMODEL * 2);
  bf16_t* U   = (bf16_t*)alloc((size_t)(2 * T_TOK + 128) * FF * 2);  // +128 row pad for tile overread
  float*  Y   = (float*)alloc((size_t)(2 * T_TOK) * DMODEL * 4);
  int*   cnt  = (int*)alloc(256);
  int*   offs = (int*)alloc(256);
  int*   tok  = (int*)alloc((size_t)NEXP * T_TOK * 4);
  float* wl   = (float*)alloc((size_t)NEXP * T_TOK * 4);
  int*   slot = (int*)alloc((size_t)2 * T_TOK * 4);
  size_t base = off;
  const size_t W1T_FULL = (size_t)NEXP * FF2 * DMODEL * 2;
  const size_t W2T_FULL = (size_t)NEXP * DMODEL * FF * 2;
  bool batched = (ws_size >= base + W1T_FULL + W2T_FULL);  // constant per process: graph-safe

  hipMemsetAsync(cnt, 0, NEXP * sizeof(int), stream);
  moe_router<<<dim3(T_TOK / 4), dim3(256), 0, stream>>>(x, Wr, temp, xb, cnt, tok, wl, slot);
  moe_prefix<<<dim3(1), dim3(64), 0, stream>>>(cnt, offs);

  if (batched) {
    bf16_t* W1t = (bf16_t*)alloc(W1T_FULL);
    bf16_t* W2t = (bf16_t*)alloc(W2T_FULL);
    tcast_fast<<<dim3(FF2 / 64, DMODEL / 64, NEXP), dim3(256), 0, stream>>>(W1, W1t, DMODEL, FF2);
    tcast_fast<<<dim3(DMODEL / 64, FF / 64, NEXP), dim3(256), 0, stream>>>(W2, W2t, FF, DMODEL);
    moe_gemm1<<<dim3(FF / 64, T_TOK / 128, NEXP), dim3(256), 0, stream>>>(
        xb, W1t, b1, cnt, offs, tok, wl, U, 0, (long)FF2 * DMODEL);
    moe_gemm2<<<dim3(DMODEL / 128, T_TOK / 128, NEXP), dim3(256), 0, stream>>>(
        U, W2t, cnt, offs, Y, 0, (long)DMODEL * FF);
  } else {
    // ws too small for all transposed weights: rotate one-expert buffers (stream-serial)
    bf16_t* W1t = (bf16_t*)alloc((size_t)FF2 * DMODEL * 2);
    bf16_t* W2t = (bf16_t*)alloc((size_t)DMODEL * FF * 2);
    for (int e = 0; e < NEXP; ++e) {
      tcast_fast<<<dim3(FF2 / 64, DMODEL / 64, 1), dim3(256), 0, stream>>>(
          W1 + (size_t)e * DMODEL * FF2, W1t, DMODEL, FF2);
      moe_gemm1<<<dim3(FF / 64, T_TOK / 128, 1), dim3(256), 0, stream>>>(
          xb, W1t, b1, cnt, offs, tok, wl, U, e, 0);
    }
    for (int e = 0; e < NEXP; ++e) {
      tcast_fast<<<dim3(DMODEL / 64, FF / 64, 1), dim3(256), 0, stream>>>(
          W2 + (size_t)e * FF * DMODEL, W2t, FF, DMODEL);
      moe_gemm2<<<dim3(DMODEL / 128, T_TOK / 128, 1), dim3(256), 0, stream>>>(
          U, W2t, cnt, offs, Y, e, 0);
    }
  }
  moe_combine<<<dim3(T_TOK), dim3(256), 0, stream>>>(Y, b2, slot, wl, offs, out);
}